// Round 16
// baseline (3802.966 us; speedup 1.0000x reference)
//
#include <hip/hip_runtime.h>
#include <cmath>

#define DD   512
#define HH   1024
#define BB   4
#define SS   4096
#define CHK  64
#define NCHK 64
#define TOK  256
#define SA   72   /* padded LDS row stride in bf16 elements */
#define GRID_BLKS 256

static constexpr float ERRSCALE = 2.0f / (float)(TOK * DD);

typedef __attribute__((ext_vector_type(8))) short bf16x8;
typedef __attribute__((ext_vector_type(4))) float f32x4;

__device__ __forceinline__ float sigmoidf_(float v) { return 1.0f / (1.0f + expf(-v)); }
__device__ __forceinline__ float clip1f_(float v) { return fminf(fmaxf(v, -1.0f), 1.0f); }

__device__ __forceinline__ ushort f2b(float f) {
    union { float f; unsigned u; } v; v.f = f;
    return (ushort)((v.u + 0x7fffu + ((v.u >> 16) & 1u)) >> 16);
}
__device__ __forceinline__ float b2f(ushort u) {
    union { unsigned u; float f; } v; v.u = ((unsigned)u) << 16;
    return v.f;
}

// Device-scope (sc1) write-through bf16 store (proven round 14).
__device__ __forceinline__ void stg16(ushort* p, ushort v) {
    asm volatile("global_store_short %0, %1, off sc1"
                 :: "v"(p), "v"((unsigned)v) : "memory");
}

// Device-coherent 16B load: two 8B AGENT-scope relaxed atomic loads
// (proven round 14). C=false: plain cached load.
template<bool C>
__device__ __forceinline__ float4 ldg16(const ushort* p) {
    if (C) {
        const unsigned long long* q = (const unsigned long long*)p;
        union { unsigned long long u[2]; float4 f; } v;
        v.u[0] = __hip_atomic_load(q,     __ATOMIC_RELAXED, __HIP_MEMORY_SCOPE_AGENT);
        v.u[1] = __hip_atomic_load(q + 1, __ATOMIC_RELAXED, __HIP_MEMORY_SCOPE_AGENT);
        return v.f;
    } else {
        return *(const float4*)p;
    }
}

// ---------------------------------------------------------------------------
// ONE-HOP grid barrier (ROUND-16 CHANGE — only delta vs round 14):
// entry vmcnt(0) drains write-through stores; each block publishes its flat
// 4B flag; EVERY thread polls one distinct flag. Barrier complete when all
// 256 flags reach target — no block-0 aggregation hop.
// ---------------------------------------------------------------------------
__device__ __forceinline__ void gbar(unsigned* flags, unsigned target) {
    asm volatile("s_waitcnt vmcnt(0)" ::: "memory");
    __syncthreads();
    if (threadIdx.x == 0)
        __hip_atomic_store(flags + blockIdx.x, target,
                           __ATOMIC_RELAXED, __HIP_MEMORY_SCOPE_AGENT);
    unsigned* f = flags + threadIdx.x;
    while (__hip_atomic_load(f, __ATOMIC_RELAXED, __HIP_MEMORY_SCOPE_AGENT) < target)
        __builtin_amdgcn_s_sleep(1);
    __syncthreads();
}

// Light block barrier: drains LDS ops only, keeps global loads in flight.
__device__ __forceinline__ void lbar() {
    __builtin_amdgcn_sched_barrier(0);
    asm volatile("s_waitcnt lgkmcnt(0)" ::: "memory");
    __builtin_amdgcn_s_barrier();
    __builtin_amdgcn_sched_barrier(0);
}

// ---------------------------------------------------------------------------
// Staging: global->regs (ld_n), regs->LDS (st_n, ds_write_b128).
// ---------------------------------------------------------------------------
template<bool C>
__device__ __forceinline__ void ld_n(const ushort* __restrict__ G, int ld,
                                     int r0, int k0, float4 r[2], int tid) {
#pragma unroll
    for (int p = 0; p < 2; ++p) {
        const int c = tid + p * 256, rr = c >> 3, o = c & 7;
        r[p] = ldg16<C>(G + (size_t)(r0 + rr) * ld + k0 + o * 8);
    }
}
__device__ __forceinline__ void st_n(const float4 r[2], ushort* S, int tid) {
#pragma unroll
    for (int p = 0; p < 2; ++p) {
        const int c = tid + p * 256, rr = c >> 3, o = c & 7;
        *(float4*)(S + rr * SA + o * 8) = r[p];
    }
}

// ---------------------------------------------------------------------------
// 64x64 block-tile MFMA core, 4 waves of 32x32, NS K-steps of 64 (compile-time
// unrolled). 3-deep global->reg prefetch, double LDS buffers, single lbar per
// K-step. (Round-14-exact.)
// ---------------------------------------------------------------------------
template<bool CA, bool CB, int NS>
__device__ __forceinline__ void gemm_core(
    const ushort* __restrict__ A, int lda,
    const ushort* __restrict__ B, int ldb,
    int m0, int n0, ushort* As, ushort* Bs, f32x4 acc[2][2])
{
    const int tid = threadIdx.x;
    const int lane = tid & 63;
    const int w = tid >> 6;
    const int wr = (w >> 1) * 32, wc = (w & 1) * 32;
    const int lr = lane & 15, lg = lane >> 4;

    float4 ra[3][2], rb[3][2];
#pragma unroll
    for (int i = 0; i < 3; ++i) {
        if (i < NS) {
            ld_n<CA>(A, lda, m0, i * 64, ra[i], tid);
            ld_n<CB>(B, ldb, n0, i * 64, rb[i], tid);
        }
    }
#pragma unroll
    for (int k = 0; k < NS; ++k) {
        const int q = k % 3;       // static under full unroll
        const int b = k & 1;
        ushort* Ab = As + b * 64 * SA;
        ushort* Bb = Bs + b * 64 * SA;
        st_n(ra[q], Ab, tid);
        st_n(rb[q], Bb, tid);
        lbar();
        if (k + 3 < NS) {
            const int kn = (k + 3) * 64;
            ld_n<CA>(A, lda, m0, kn, ra[q], tid);
            ld_n<CB>(B, ldb, n0, kn, rb[q], tid);
        }
#pragma unroll
        for (int ks = 0; ks < 2; ++ks) {
            bf16x8 af[2], bfr[2];
#pragma unroll
            for (int mi = 0; mi < 2; ++mi)
                af[mi] = *(const bf16x8*)(Ab + (wr + mi * 16 + lr) * SA + ks * 32 + lg * 8);
#pragma unroll
            for (int ni = 0; ni < 2; ++ni)
                bfr[ni] = *(const bf16x8*)(Bb + (wc + ni * 16 + lr) * SA + ks * 32 + lg * 8);
#pragma unroll
            for (int mi = 0; mi < 2; ++mi)
#pragma unroll
                for (int ni = 0; ni < 2; ++ni)
                    acc[mi][ni] = __builtin_amdgcn_mfma_f32_16x16x32_bf16(
                        af[mi], bfr[ni], acc[mi][ni], 0, 0, 0);
        }
    }
}

// Per-element compute iterator. C/D layout: col=lane&15, row=(lane>>4)*4+reg.
template<typename F>
__device__ __forceinline__ void epilogue_i(int m0, int n0, const f32x4 acc[2][2], F&& f) {
    const int lane = threadIdx.x & 63, w = threadIdx.x >> 6;
    const int wr = (w >> 1) * 32, wc = (w & 1) * 32;
    const int lr = lane & 15, lg = lane >> 4;
#pragma unroll
    for (int mi = 0; mi < 2; ++mi)
#pragma unroll
        for (int ni = 0; ni < 2; ++ni)
#pragma unroll
            for (int r = 0; r < 4; ++r)
                f(mi * 8 + ni * 4 + r,
                  m0 + wr + mi * 16 + lg * 4 + r, n0 + wc + ni * 16 + lr, acc[mi][ni][r]);
}

__device__ __forceinline__ void zacc(f32x4 acc[2][2]) {
#pragma unroll
    for (int i = 0; i < 2; ++i)
#pragma unroll
        for (int j = 0; j < 2; ++j) acc[i][j] = 0.0f;
}

// ---------------------------------------------------------------------------
// Scan phase ops (round-14-exact).
// ---------------------------------------------------------------------------
__device__ __forceinline__ void op_s1(const ushort* kt, const ushort* W1e,
                                      ushort* a1, ushort* a1t,
                                      float (&dsr)[16], int m0, int n0,
                                      ushort* As, ushort* Bs) {
    f32x4 acc[2][2]; zacc(acc);
    gemm_core<false, true, 8>(kt, DD, W1e, DD, m0, n0, As, Bs, acc);
    epilogue_i(m0, n0, acc, [&](int idx, int r, int c, float v) {
        const float sg = sigmoidf_(v);
        const ushort bv = f2b(v * sg);
        stg16(a1 + (size_t)r * HH + c, bv);
        stg16(a1t + (size_t)c * TOK + r, bv);
        dsr[idx] = sg * (1.0f + v * (1.0f - sg));   // silu' kept in registers
    });
}

__device__ __forceinline__ void op_s2(const ushort* a1, const ushort* W2e,
                                      const ushort* vt, ushort* db2, ushort* db2t,
                                      int m0, int n0, ushort* As, ushort* Bs) {
    f32x4 acc[2][2]; zacc(acc);
    gemm_core<true, true, 16>(a1, HH, W2e, HH, m0, n0, As, Bs, acc);
    epilogue_i(m0, n0, acc, [&](int idx, int r, int c, float v) {
        const size_t i = (size_t)r * DD + c;
        const float e = clip1f_(v - b2f(vt[i]));
        const ushort bv = f2b(e * ERRSCALE);
        stg16(db2 + i, bv);
        stg16(db2t + (size_t)c * TOK + r, bv);
    });
}

// s3: db1t = ((db2 @ W2e) * silu') written TRANSPOSED only.
__device__ __forceinline__ void op_s3(const ushort* db2, const ushort* W2eT,
                                      const float (&dsr)[16], ushort* db1t,
                                      int m0, int n0, ushort* As, ushort* Bs) {
    f32x4 acc[2][2]; zacc(acc);
    gemm_core<true, true, 8>(db2, DD, W2eT, DD, m0, n0, As, Bs, acc);
    epilogue_i(m0, n0, acc, [&](int idx, int r, int c, float v) {
        stg16(db1t + (size_t)c * TOK + r, f2b(v * dsr[idx]));
    });
}

// ktt transpose (P1, idle blocks 0-63): kt [TOK][DD] -> ktt [DD][TOK]
__device__ __forceinline__ void op_ktt(const ushort* kt, ushort* ktt, int lbid) {
    const int g = lbid * 256 + threadIdx.x;       // 0..16383
    const int m = g >> 6;
    const int d0 = (g & 63) * 8;
    const float4 v = *(const float4*)(kt + (size_t)m * DD + d0);
    ushort u[8]; __builtin_memcpy(u, &v, 16);
#pragma unroll
    for (int j = 0; j < 8; ++j) stg16(ktt + (size_t)(d0 + j) * TOK + m, u[j]);
}

// Gradient GEMM (both operands pre-transposed, k over TOK) + register-resident
// state update; publishes W_new (and W_newT for g2).
template<int LD, bool WT>
__device__ __forceinline__ void op_gupd(
    const ushort* __restrict__ At, const ushort* __restrict__ Bt,
    float (&sm)[16], float (&sd)[16], const float (&swm)[16],
    ushort* __restrict__ Wn, ushort* __restrict__ WnT,
    float dec, float lrg, float eta,
    int i0, int j0, ushort* As, ushort* Bs)
{
    f32x4 acc[2][2]; zacc(acc);
    gemm_core<true, true, 4>(At, TOK, Bt, TOK, i0, j0, As, Bs, acc);
    epilogue_i(i0, j0, acc, [&](int idx, int row, int col, float v) {
        const float g = clip1f_(v);
        const float mn = eta * sm[idx] - lrg * g;
        sm[idx] = mn;
        const float dn = (1.0f - dec) * sd[idx] + mn;
        sd[idx] = dn;
        const ushort wv = f2b(swm[idx] + dn);
        stg16(Wn + (size_t)row * LD + col, wv);
        if (WT) stg16(WnT + (size_t)col * DD + row, wv);   // [H,D] stride DD
    });
}

__device__ __forceinline__ void op_s6(const ushort* qt, const ushort* W1e,
                                      ushort* h, int m0, int n0,
                                      ushort* As, ushort* Bs) {
    f32x4 acc[2][2]; zacc(acc);
    gemm_core<false, true, 8>(qt, DD, W1e, DD, m0, n0, As, Bs, acc);
    epilogue_i(m0, n0, acc, [&](int idx, int r, int c, float v) {
        const float sg = sigmoidf_(v);
        stg16(h + (size_t)r * HH + c, f2b(v * sg));
    });
}

__device__ __forceinline__ void op_s7(const ushort* h, const ushort* W2e,
                                      ushort* y, int m0, int n0,
                                      ushort* As, ushort* Bs) {
    f32x4 acc[2][2]; zacc(acc);
    gemm_core<true, true, 16>(h, HH, W2e, HH, m0, n0, As, Bs, acc);
    epilogue_i(m0, n0, acc, [&](int idx, int r, int c, float v) {
        stg16(y + (size_t)r * DD + c, f2b(v));
    });
}

// ---------------------------------------------------------------------------
// Persistent scan kernel (round 14 structure; one-hop barrier).
//   blocks   0- 63: ktt transpose (P1), s6/s7/s2 (P3/P4)
//   blocks  64-127: s1/s3 (same tiles -> silu' stays in registers)
//   blocks 128-255: g2 state tile AND g1 state tile (registers)
// 4 grid barriers per chunk:
//   P1 = ktt || s3(t) || g2upd(t); P2 = g1upd(t); P3 = s6(t) || s1(t+1);
//   P4 = s7(t) || s2(t+1).  Weights/activations parity double-buffered.
// ---------------------------------------------------------------------------
struct ScanArgs {
    const ushort *ktb, *vcb, *qtb;
    ushort *a1b0, *a1b1, *a1t0, *a1t1;
    ushort *db1t, *db2b0, *db2b1, *db2t0, *db2t1, *hbb, *kttb;
    ushort *W1eb0, *W1eb1, *W2eb0, *W2eb1, *W2eT0, *W2eT1;
    const float *Wm1, *Wm2, *gates;
    ushort *ycall;
    unsigned *flags;
};

__global__ __launch_bounds__(256, 1) void scan_k(ScanArgs p) {
    __shared__ ushort As[2 * 64 * SA];
    __shared__ ushort Bs[2 * 64 * SA];
    const int bid = blockIdx.x;
    unsigned bt = 0;

    const int lane = threadIdx.x & 63, w = threadIdx.x >> 6;
    const int wr = (w >> 1) * 32, wc = (w & 1) * 32;
    const int lr = lane & 15, lg = lane >> 4;

    float dsr[16];                                   // blocks 64-127
    float sm1[16], sd1[16], swm1[16];                // blocks 128-255: g1 tile [H,D]
    float sm2[16], sd2[16], swm2[16];                // blocks 128-255: g2 tile [D,H]
    int g1i0 = 0, g1j0 = 0, g2i0 = 0, g2j0 = 0;
    if (bid >= 128) {
        const int L = bid - 128;
        g2i0 = (L >> 4) * 64; g2j0 = (L & 15) * 64;
        g1i0 = (L >> 3) * 64; g1j0 = (L & 7) * 64;
#pragma unroll
        for (int mi = 0; mi < 2; ++mi)
#pragma unroll
            for (int ni = 0; ni < 2; ++ni)
#pragma unroll
                for (int r = 0; r < 4; ++r) {
                    const int idx = mi * 8 + ni * 4 + r;
                    const int ro = wr + mi * 16 + lg * 4 + r;
                    const int co = wc + ni * 16 + lr;
                    swm2[idx] = p.Wm2[(size_t)(g2i0 + ro) * HH + (g2j0 + co)];
                    swm1[idx] = p.Wm1[(size_t)(g1i0 + ro) * DD + (g1j0 + co)];
                    sm1[idx] = 0.0f; sd1[idx] = 0.0f;
                    sm2[idx] = 0.0f; sd2[idx] = 0.0f;
                }
    }

    // ---- prologue: chunk-0 forward ----
    if (bid >= 64 && bid < 128) {
        const int L = bid - 64;
        op_s1(p.ktb, p.W1eb0, p.a1b0, p.a1t0, dsr,
              (L >> 4) * 64, (L & 15) * 64, As, Bs);
    }
    gbar(p.flags, ++bt);
    if (bid >= 32 && bid < 64) {
        const int L = bid - 32;
        op_s2(p.a1b0, p.W2eb0, p.vcb, p.db2b0, p.db2t0,
              (L >> 3) * 64, (L & 7) * 64, As, Bs);
    }
    gbar(p.flags, ++bt);

    for (int t = 0; t < NCHK; ++t) {
        const int par = t & 1;
        const ushort* kt  = p.ktb + (size_t)t * TOK * DD;
        const ushort* qt  = p.qtb + (size_t)t * TOK * DD;
        ushort* a1n   = par ? p.a1b0 : p.a1b1;
        ushort* a1tn  = par ? p.a1t0 : p.a1t1;
        ushort* a1tc  = par ? p.a1t1 : p.a1t0;
        ushort* db2c  = par ? p.db2b1 : p.db2b0;
        ushort* db2n  = par ? p.db2b0 : p.db2b1;
        ushort* db2tc = par ? p.db2t1 : p.db2t0;
        ushort* db2tn = par ? p.db2t0 : p.db2t1;
        ushort* W1n   = par ? p.W1eb0 : p.W1eb1;
        const ushort* W2oT = par ? p.W2eT1 : p.W2eT0;
        ushort* W2n   = par ? p.W2eb0 : p.W2eb1;
        ushort* W2nT  = par ? p.W2eT0 : p.W2eT1;
        const float dec = p.gates[t];
        const float lrg = p.gates[NCHK + t];
        const float eta = p.gates[2 * NCHK + t];

        // P1: ktt (0-63) || s3 (64-127, dsr in regs) || g2upd (128-255)
        if (bid < 64) {
            op_ktt(kt, p.kttb, bid);
        } else if (bid < 128) {
            const int L = bid - 64;
            op_s3(db2c, W2oT, dsr, p.db1t, (L >> 4) * 64, (L & 15) * 64, As, Bs);
        } else {
            op_gupd<HH, true>(db2tc, a1tc, sm2, sd2, swm2, W2n, W2nT,
                              dec, lrg, eta, g2i0, g2j0, As, Bs);
        }
        gbar(p.flags, ++bt);

        // P2: g1upd (128-255, reg state)
        if (bid >= 128) {
            op_gupd<DD, false>(p.db1t, p.kttb, sm1, sd1, swm1, W1n, nullptr,
                               dec, lrg, eta, g1i0, g1j0, As, Bs);
        }
        gbar(p.flags, ++bt);

        // P3: s6(t) (0-63) || s1(t+1) (64-127)
        if (bid < 64) {
            op_s6(qt, W1n, p.hbb, (bid >> 4) * 64, (bid & 15) * 64, As, Bs);
        } else if (bid < 128 && t + 1 < NCHK) {
            const int L = bid - 64;
            op_s1(p.ktb + (size_t)(t + 1) * TOK * DD, W1n, a1n, a1tn, dsr,
                  (L >> 4) * 64, (L & 15) * 64, As, Bs);
        }
        gbar(p.flags, ++bt);

        // P4: s7(t) (0-31) || s2(t+1) (32-63)
        if (bid < 32) {
            op_s7(p.hbb, W2n, p.ycall + (size_t)t * TOK * DD,
                  (bid >> 3) * 64, (bid & 7) * 64, As, Bs);
        } else if (bid < 64 && t + 1 < NCHK) {
            const int L = bid - 32;
            op_s2(a1n, W2n, p.vcb + (size_t)(t + 1) * TOK * DD, db2n, db2tn,
                  (L >> 3) * 64, (L & 7) * 64, As, Bs);
        }
        gbar(p.flags, ++bt);
    }
}

// ---------------------------------------------------------------------------
// Pre/post kernels (separate launches; plain cached loads/stores)
// ---------------------------------------------------------------------------
__global__ __launch_bounds__(256) void conv_k(const float* __restrict__ s,
                                              ushort* __restrict__ d, int n4) {
    const int i = blockIdx.x * 256 + threadIdx.x;
    if (i < n4) {
        const float4 v = ((const float4*)s)[i];
        ushort4 o;
        o.x = f2b(v.x); o.y = f2b(v.y); o.z = f2b(v.z); o.w = f2b(v.w);
        ((ushort4*)d)[i] = o;
    }
}

// Transposed conversion: s [R][C] f32 -> d [C][R] bf16 (for initial W2eT)
__global__ __launch_bounds__(256) void convT_k(const float* __restrict__ s,
                                               ushort* __restrict__ d, int R, int C) {
    const int i = blockIdx.x * 256 + threadIdx.x;
    if (i < R * C) {
        const int r = i / C, c = i % C;
        d[(size_t)c * R + r] = f2b(s[i]);
    }
}

template<int OM>
__global__ __launch_bounds__(256) void proj_k(const ushort* __restrict__ xb,
                                              const ushort* __restrict__ Wb,
                                              float* __restrict__ df,
                                              ushort* __restrict__ db) {
    __shared__ ushort As[2 * 64 * SA], Bs[2 * 64 * SA];
    f32x4 acc[2][2]; zacc(acc);
    const int m0 = blockIdx.y * 64, n0 = blockIdx.x * 64;
    gemm_core<false, false, 8>(xb, DD, Wb, DD, m0, n0, As, Bs, acc);
    epilogue_i(m0, n0, acc, [&](int idx, int row, int col, float val) {
        const int b = row >> 12, s = row & (SS - 1);
        const int t = s >> 6, c = s & 63;
        const size_t orow = (size_t)((t << 8) | (b << 6) | c);
        if (OM == 0) df[orow * DD + col] = val;
        else         db[orow * DD + col] = f2b(val);
    });
}

__global__ __launch_bounds__(256) void l2n_k(const float* __restrict__ kp,
                                             const float* __restrict__ qp,
                                             ushort* __restrict__ kb,
                                             ushort* __restrict__ qb) {
    const float* src = blockIdx.y ? qp : kp;
    ushort* dst = blockIdx.y ? qb : kb;
    const int row = blockIdx.x * 4 + (threadIdx.x >> 6);
    const int lane = threadIdx.x & 63;
    const float4* p = (const float4*)(src + (size_t)row * DD);
    float4 v0 = p[lane], v1 = p[lane + 64];
    float ss = v0.x * v0.x + v0.y * v0.y + v0.z * v0.z + v0.w * v0.w
             + v1.x * v1.x + v1.y * v1.y + v1.z * v1.z + v1.w * v1.w;
#pragma unroll
    for (int m = 32; m >= 1; m >>= 1) ss += __shfl_xor(ss, m);
    const float sc = 1.0f / (sqrtf(ss) + 1e-8f);
    ushort4 o0, o1;
    o0.x = f2b(v0.x * sc); o0.y = f2b(v0.y * sc); o0.z = f2b(v0.z * sc); o0.w = f2b(v0.w * sc);
    o1.x = f2b(v1.x * sc); o1.y = f2b(v1.y * sc); o1.z = f2b(v1.z * sc); o1.w = f2b(v1.w * sc);
    *(ushort4*)(dst + (size_t)row * DD + lane * 4) = o0;
    *(ushort4*)(dst + (size_t)row * DD + 256 + lane * 4) = o1;
}

__global__ __launch_bounds__(256) void gates_tok_k(
    const float* __restrict__ x,
    const float* __restrict__ gdw, const float* __restrict__ gdb,
    const float* __restrict__ glw, const float* __restrict__ glb,
    const float* __restrict__ gmw, const float* __restrict__ gmb,
    float* __restrict__ gtok)
{
    const int wid = (blockIdx.x * 256 + threadIdx.x) >> 6;
    const int lane = threadIdx.x & 63;
    const int t = wid >> 8;
    const int rem = wid & 255;
    const int b = rem >> 6;
    const int c = rem & 63;
    const float* xr = x + ((size_t)b * SS + (size_t)t * CHK + c) * DD;
    float s0 = 0.0f, s1 = 0.0f, s2 = 0.0f;
#pragma unroll
    for (int jj = 0; jj < DD / 64; ++jj) {
        const int j = lane + jj * 64;
        const float xv = xr[j];
        s0 = fmaf(xv, gdw[j], s0);
        s1 = fmaf(xv, glw[j], s1);
        s2 = fmaf(xv, gmw[j], s2);
    }
#pragma unroll
    for (int m = 32; m >= 1; m >>= 1) {
        s0 += __shfl_xor(s0, m);
        s1 += __shfl_xor(s1, m);
        s2 += __shfl_xor(s2, m);
    }
    if (lane == 0) {
        gtok[0 * (NCHK * TOK) + wid] = sigmoidf_(s0 + gdb[0]);
        gtok[1 * (NCHK * TOK) + wid] = sigmoidf_(s1 + glb[0]);
        gtok[2 * (NCHK * TOK) + wid] = sigmoidf_(s2 + gmb[0]);
    }
}

__global__ __launch_bounds__(256) void gates_red_k(
    const float* __restrict__ gtok, float* __restrict__ gates)
{
    __shared__ float sm[256];
    const int t = blockIdx.x;
    for (int g = 0; g < 3; ++g) {
        sm[threadIdx.x] = gtok[g * (NCHK * TOK) + t * TOK + threadIdx.x];
        __syncthreads();
        for (int s = 128; s >= 1; s >>= 1) {
            if (threadIdx.x < s) sm[threadIdx.x] += sm[threadIdx.x + s];
            __syncthreads();
        }
        if (threadIdx.x == 0) gates[g * NCHK + t] = sm[0] * (1.0f / 256.0f);
        __syncthreads();
    }
}

__global__ __launch_bounds__(256) void out_k(const ushort* __restrict__ ycall,
                                             const ushort* __restrict__ Woutb,
                                             float* __restrict__ out) {
    __shared__ ushort As[2 * 64 * SA], Bs[2 * 64 * SA];
    f32x4 acc[2][2]; zacc(acc);
    const int m0 = blockIdx.y * 64, n0 = blockIdx.x * 64;
    gemm_core<false, false, 8>(ycall, DD, Woutb, DD, m0, n0, As, Bs, acc);
    epilogue_i(m0, n0, acc, [&](int idx, int row, int col, float val) {
        const int t = row >> 8, b = (row >> 6) & 3, c = row & 63;
        out[((size_t)b * SS + (size_t)t * CHK + c) * DD + col] = val;
    });
}

// ---------------------------------------------------------------------------
extern "C" void kernel_launch(void* const* d_in, const int* in_sizes, int n_in,
                              void* d_out, int out_size, void* d_ws, size_t ws_size,
                              hipStream_t stream)
{
    const float* x    = (const float*)d_in[0];
    const float* Wk   = (const float*)d_in[1];
    const float* Wv   = (const float*)d_in[2];
    const float* Wq   = (const float*)d_in[3];
    const float* Wout = (const float*)d_in[4];
    const float* Wm1  = (const float*)d_in[5];
    const float* Wm2  = (const float*)d_in[6];
    const float* gdw  = (const float*)d_in[7];
    const float* gdb  = (const float*)d_in[8];
    const float* glw  = (const float*)d_in[9];
    const float* glb  = (const float*)d_in[10];
    const float* gmw  = (const float*)d_in[11];
    const float* gmb  = (const float*)d_in[12];
    float* out = (float*)d_out;

    char* w = (char*)d_ws;
    size_t off = 0;
    auto alloc = [&](size_t bytes) {
        off = (off + 255) & ~(size_t)255;
        char* p = w + off;
        off += bytes;
        return p;
    };

    const size_t M = (size_t)BB * SS;                 // 16384
    float*  kpre = (float*)alloc(M * DD * 4);         // f32 chunk-major; ycall aliases
    char*   qreg = alloc(M * DD * 4);                 // qpre f32; scan temps alias after l2n
    float*  qpre = (float*)qreg;
    ushort* xb   = (ushort*)alloc(M * DD * 2);        // ktb aliases after projections
    ushort* qtb  = (ushort*)alloc(M * DD * 2);
    ushort* vcb  = (ushort*)alloc(M * DD * 2);
    ushort* Wkb  = (ushort*)alloc((size_t)DD * DD * 2);
    ushort* Wvb  = (ushort*)alloc((size_t)DD * DD * 2);
    ushort* Wqb  = (ushort*)alloc((size_t)DD * DD * 2);
    ushort* Woutb= (ushort*)alloc((size_t)DD * DD * 2);
    float*  gtok = (float*)alloc((size_t)3 * NCHK * TOK * 4);
    float*  gates= (float*)alloc((size_t)3 * NCHK * 4);
    unsigned* bar = (unsigned*)alloc((size_t)1024);

    ushort* ktb   = xb;             // alias: xb dead after projection GEMMs
    ushort* ycall = (ushort*)kpre;  // alias: kpre dead after l2norm

    // scan temporaries carved from qpre region (dead after l2n):
    size_t qo = 0;
    auto qalloc = [&](size_t bytes) { char* p = qreg + qo; qo += bytes; return p; };
    ushort* a1b0  = (ushort*)qalloc((size_t)TOK * HH * 2);
    ushort* a1b1  = (ushort*)qalloc((size_t)TOK * HH * 2);
    ushort* a1t0  = (ushort*)qalloc((size_t)TOK * HH * 2);
    ushort* a1t1  = (ushort*)qalloc((size_t)TOK * HH * 2);
    ushort* db1t  = (ushort*)qalloc((size_t)TOK * HH * 2);
    ushort* db2b0 = (ushort*)qalloc((size_t)TOK * DD * 2);
    ushort* db2b1 = (ushort*)qalloc((size_t)TOK * DD * 2);
    ushort* db2t0 = (ushort*)qalloc((size_t)TOK * DD * 2);
    ushort* db2t1 = (ushort*)qalloc((size_t)TOK * DD * 2);
    ushort* hbb   = (ushort*)qalloc((size_t)TOK * HH * 2);
    ushort* kttb  = (ushort*)qalloc((size_t)TOK * DD * 2);
    ushort* W1eb0 = (ushort*)qalloc((size_t)HH * DD * 2);
    ushort* W1eb1 = (ushort*)qalloc((size_t)HH * DD * 2);
    ushort* W2eb0 = (ushort*)qalloc((size_t)HH * DD * 2);
    ushort* W2eb1 = (ushort*)qalloc((size_t)HH * DD * 2);
    ushort* W2eT0 = (ushort*)qalloc((size_t)HH * DD * 2);
    ushort* W2eT1 = (ushort*)qalloc((size_t)HH * DD * 2);

    // zero the barrier flags
    hipMemsetAsync(bar, 0, (size_t)1024, stream);

    const dim3 blk(256);

    // bf16 conversions of x and projection weights
    conv_k<<<dim3((M * DD / 4 + 255) / 256), blk, 0, stream>>>(x, xb, (int)(M * DD / 4));
    conv_k<<<dim3((DD * DD / 4 + 255) / 256), blk, 0, stream>>>(Wk, Wkb, DD * DD / 4);
    conv_k<<<dim3((DD * DD / 4 + 255) / 256), blk, 0, stream>>>(Wv, Wvb, DD * DD / 4);
    conv_k<<<dim3((DD * DD / 4 + 255) / 256), blk, 0, stream>>>(Wq, Wqb, DD * DD / 4);
    conv_k<<<dim3((DD * DD / 4 + 255) / 256), blk, 0, stream>>>(Wout, Woutb, DD * DD / 4);

    // projections (chunk-major epilogue)
    proj_k<0><<<dim3(DD / 64, M / 64), blk, 0, stream>>>(xb, Wkb, kpre, nullptr);
    proj_k<1><<<dim3(DD / 64, M / 64), blk, 0, stream>>>(xb, Wvb, nullptr, vcb);
    proj_k<0><<<dim3(DD / 64, M / 64), blk, 0, stream>>>(xb, Wqb, qpre, nullptr);

    // l2norm + bf16 (ktb aliases xb; qpre consumed here)
    l2n_k<<<dim3(M / 4, 2), blk, 0, stream>>>(kpre, qpre, ktb, qtb);

    // initial effective weights (into qpre region — now dead)
    conv_k<<<dim3((HH * DD / 4 + 255) / 256), blk, 0, stream>>>(Wm1, W1eb0, HH * DD / 4);
    conv_k<<<dim3((HH * DD / 4 + 255) / 256), blk, 0, stream>>>(Wm2, W2eb0, HH * DD / 4);
    convT_k<<<dim3((DD * HH + 255) / 256), blk, 0, stream>>>(Wm2, W2eT0, DD, HH);

    // gates
    gates_tok_k<<<dim3(M / 4), blk, 0, stream>>>(x, gdw, gdb, glw, glb, gmw, gmb, gtok);
    gates_red_k<<<dim3(NCHK), blk, 0, stream>>>(gtok, gates);

    // persistent scan (all 64 chunks)
    ScanArgs sa;
    sa.ktb = ktb; sa.vcb = vcb; sa.qtb = qtb;
    sa.a1b0 = a1b0; sa.a1b1 = a1b1; sa.a1t0 = a1t0; sa.a1t1 = a1t1;
    sa.db1t = db1t; sa.db2b0 = db2b0; sa.db2b1 = db2b1;
    sa.db2t0 = db2t0; sa.db2t1 = db2t1; sa.hbb = hbb; sa.kttb = kttb;
    sa.W1eb0 = W1eb0; sa.W1eb1 = W1eb1; sa.W2eb0 = W2eb0; sa.W2eb1 = W2eb1;
    sa.W2eT0 = W2eT0; sa.W2eT1 = W2eT1;
    sa.Wm1 = Wm1; sa.Wm2 = Wm2; sa.gates = gates;
    sa.ycall = ycall;
    sa.flags = bar;
    scan_k<<<dim3(GRID_BLKS), blk, 0, stream>>>(sa);

    // final projection + scatter to [B,S,D]
    out_k<<<dim3(DD / 64, M / 64), blk, 0, stream>>>(ycall, Woutb, out);
}

// Round 17
// 2129.361 us; speedup vs baseline: 1.7860x; 1.7860x over previous
//
#include <hip/hip_runtime.h>
#include <cmath>

#define DD   512
#define HH   1024
#define BB   4
#define SS   4096
#define CHK  64
#define NCHK 64
#define TOK  256
#define SA   72   /* padded LDS row stride in bf16 elements */
#define GRID_BLKS 256
#define FLAG_STRIDE 16   /* u32s per flag slot = 64B */

static constexpr float ERRSCALE = 2.0f / (float)(TOK * DD);

typedef __attribute__((ext_vector_type(8))) short bf16x8;
typedef __attribute__((ext_vector_type(4))) float f32x4;
typedef __attribute__((ext_vector_type(2))) unsigned u32x2;

__device__ __forceinline__ float sigmoidf_(float v) { return 1.0f / (1.0f + expf(-v)); }
__device__ __forceinline__ float clip1f_(float v) { return fminf(fmaxf(v, -1.0f), 1.0f); }

__device__ __forceinline__ ushort f2b(float f) {
    union { float f; unsigned u; } v; v.f = f;
    return (ushort)((v.u + 0x7fffu + ((v.u >> 16) & 1u)) >> 16);
}
__device__ __forceinline__ float b2f(ushort u) {
    union { unsigned u; float f; } v; v.u = ((unsigned)u) << 16;
    return v.f;
}

// Device-scope (sc1) write-through stores (proven round 14).
__device__ __forceinline__ void stg16(ushort* p, ushort v) {
    asm volatile("global_store_short %0, %1, off sc1"
                 :: "v"(p), "v"((unsigned)v) : "memory");
}
__device__ __forceinline__ void stg64(ushort* p, u32x2 v) {
    asm volatile("global_store_dwordx2 %0, %1, off sc1"
                 :: "v"(p), "v"(v) : "memory");
}
__device__ __forceinline__ void stg128v(ushort* p, f32x4 v) {
    asm volatile("global_store_dwordx4 %0, %1, off sc1"
                 :: "v"(p), "v"(v) : "memory");
}
__device__ __forceinline__ u32x2 pack4(const ushort u[4]) {
    u32x2 v; __builtin_memcpy(&v, u, 8); return v;
}

// Device-coherent 16B load: two 8B AGENT-scope relaxed atomic loads
// (proven round 14). C=false: plain cached load.
template<bool C>
__device__ __forceinline__ float4 ldg16(const ushort* p) {
    if (C) {
        const unsigned long long* q = (const unsigned long long*)p;
        union { unsigned long long u[2]; float4 f; } v;
        v.u[0] = __hip_atomic_load(q,     __ATOMIC_RELAXED, __HIP_MEMORY_SCOPE_AGENT);
        v.u[1] = __hip_atomic_load(q + 1, __ATOMIC_RELAXED, __HIP_MEMORY_SCOPE_AGENT);
        return v.f;
    } else {
        return *(const float4*)p;
    }
}

// ---------------------------------------------------------------------------
// Two-level grid barrier (round-14-exact, proven best).
// ---------------------------------------------------------------------------
__device__ __forceinline__ void gbar(unsigned* flags, unsigned* gen, unsigned target) {
    asm volatile("s_waitcnt vmcnt(0)" ::: "memory");
    __syncthreads();
    if (blockIdx.x == 0) {
        if (threadIdx.x != 0) {
            unsigned* f = flags + (size_t)threadIdx.x * FLAG_STRIDE;
            while (__hip_atomic_load(f, __ATOMIC_RELAXED, __HIP_MEMORY_SCOPE_AGENT) < target)
                __builtin_amdgcn_s_sleep(1);
        }
        __syncthreads();
        if (threadIdx.x == 0)
            __hip_atomic_store(gen, target, __ATOMIC_RELAXED, __HIP_MEMORY_SCOPE_AGENT);
    } else {
        if (threadIdx.x == 0) {
            __hip_atomic_store(flags + (size_t)blockIdx.x * FLAG_STRIDE, target,
                               __ATOMIC_RELAXED, __HIP_MEMORY_SCOPE_AGENT);
            while (__hip_atomic_load(gen, __ATOMIC_RELAXED, __HIP_MEMORY_SCOPE_AGENT) < target)
                __builtin_amdgcn_s_sleep(1);
        }
    }
    __syncthreads();
}

// Light block barrier: drains LDS ops only, keeps global loads in flight.
__device__ __forceinline__ void lbar() {
    __builtin_amdgcn_sched_barrier(0);
    asm volatile("s_waitcnt lgkmcnt(0)" ::: "memory");
    __builtin_amdgcn_s_barrier();
    __builtin_amdgcn_sched_barrier(0);
}

// ---------------------------------------------------------------------------
// Staging: global->regs (ld_n), regs->LDS (st_n, ds_write_b128).
// ---------------------------------------------------------------------------
template<bool C>
__device__ __forceinline__ void ld_n(const ushort* __restrict__ G, int ld,
                                     int r0, int k0, float4 r[2], int tid) {
#pragma unroll
    for (int p = 0; p < 2; ++p) {
        const int c = tid + p * 256, rr = c >> 3, o = c & 7;
        r[p] = ldg16<C>(G + (size_t)(r0 + rr) * ld + k0 + o * 8);
    }
}
__device__ __forceinline__ void st_n(const float4 r[2], ushort* S, int tid) {
#pragma unroll
    for (int p = 0; p < 2; ++p) {
        const int c = tid + p * 256, rr = c >> 3, o = c & 7;
        *(float4*)(S + rr * SA + o * 8) = r[p];
    }
}

// ---------------------------------------------------------------------------
// 64x64 block-tile MFMA core, 4 waves of 32x32, NS K-steps of 64 (compile-time
// unrolled). 3-deep global->reg prefetch, double LDS buffers, single lbar per
// K-step. (Round-14-exact.)
// ---------------------------------------------------------------------------
template<bool CA, bool CB, int NS>
__device__ __forceinline__ void gemm_core(
    const ushort* __restrict__ A, int lda,
    const ushort* __restrict__ B, int ldb,
    int m0, int n0, ushort* As, ushort* Bs, f32x4 acc[2][2])
{
    const int tid = threadIdx.x;
    const int lane = tid & 63;
    const int w = tid >> 6;
    const int wr = (w >> 1) * 32, wc = (w & 1) * 32;
    const int lr = lane & 15, lg = lane >> 4;

    float4 ra[3][2], rb[3][2];
#pragma unroll
    for (int i = 0; i < 3; ++i) {
        if (i < NS) {
            ld_n<CA>(A, lda, m0, i * 64, ra[i], tid);
            ld_n<CB>(B, ldb, n0, i * 64, rb[i], tid);
        }
    }
#pragma unroll
    for (int k = 0; k < NS; ++k) {
        const int q = k % 3;       // static under full unroll
        const int b = k & 1;
        ushort* Ab = As + b * 64 * SA;
        ushort* Bb = Bs + b * 64 * SA;
        st_n(ra[q], Ab, tid);
        st_n(rb[q], Bb, tid);
        lbar();
        if (k + 3 < NS) {
            const int kn = (k + 3) * 64;
            ld_n<CA>(A, lda, m0, kn, ra[q], tid);
            ld_n<CB>(B, ldb, n0, kn, rb[q], tid);
        }
#pragma unroll
        for (int ks = 0; ks < 2; ++ks) {
            bf16x8 af[2], bfr[2];
#pragma unroll
            for (int mi = 0; mi < 2; ++mi)
                af[mi] = *(const bf16x8*)(Ab + (wr + mi * 16 + lr) * SA + ks * 32 + lg * 8);
#pragma unroll
            for (int ni = 0; ni < 2; ++ni)
                bfr[ni] = *(const bf16x8*)(Bb + (wc + ni * 16 + lr) * SA + ks * 32 + lg * 8);
#pragma unroll
            for (int mi = 0; mi < 2; ++mi)
#pragma unroll
                for (int ni = 0; ni < 2; ++ni)
                    acc[mi][ni] = __builtin_amdgcn_mfma_f32_16x16x32_bf16(
                        af[mi], bfr[ni], acc[mi][ni], 0, 0, 0);
        }
    }
}

// Per-element compute iterator. C/D layout: col=lane&15, row=(lane>>4)*4+reg.
template<typename F>
__device__ __forceinline__ void epilogue_i(int m0, int n0, const f32x4 acc[2][2], F&& f) {
    const int lane = threadIdx.x & 63, w = threadIdx.x >> 6;
    const int wr = (w >> 1) * 32, wc = (w & 1) * 32;
    const int lr = lane & 15, lg = lane >> 4;
#pragma unroll
    for (int mi = 0; mi < 2; ++mi)
#pragma unroll
        for (int ni = 0; ni < 2; ++ni)
#pragma unroll
            for (int r = 0; r < 4; ++r)
                f(mi * 8 + ni * 4 + r,
                  m0 + wr + mi * 16 + lg * 4 + r, n0 + wc + ni * 16 + lr, acc[mi][ni][r]);
}

__device__ __forceinline__ void zacc(f32x4 acc[2][2]) {
#pragma unroll
    for (int i = 0; i < 2; ++i)
#pragma unroll
        for (int j = 0; j < 2; ++j) acc[i][j] = 0.0f;
}

// ---------------------------------------------------------------------------
// Scan phase ops. ROUND-17 CHANGE: transposed epilogue copies pack the 4
// consecutive r-values into one 8B store (same values, same addresses).
// ---------------------------------------------------------------------------
__device__ __forceinline__ void op_s1(const ushort* kt, const ushort* W1e,
                                      ushort* a1, ushort* a1t,
                                      float (&dsr)[16], int m0, int n0,
                                      ushort* As, ushort* Bs) {
    f32x4 acc[2][2]; zacc(acc);
    gemm_core<false, true, 8>(kt, DD, W1e, DD, m0, n0, As, Bs, acc);
    const int lane = threadIdx.x & 63, w = threadIdx.x >> 6;
    const int wr = (w >> 1) * 32, wc = (w & 1) * 32;
    const int lr = lane & 15, lg = lane >> 4;
#pragma unroll
    for (int mi = 0; mi < 2; ++mi)
#pragma unroll
        for (int ni = 0; ni < 2; ++ni) {
            const int col = n0 + wc + ni * 16 + lr;
            const int rowb = m0 + wr + mi * 16 + lg * 4;
            ushort pv[4];
#pragma unroll
            for (int r = 0; r < 4; ++r) {
                const int idx = mi * 8 + ni * 4 + r;
                const float v = acc[mi][ni][r];
                const float sg = sigmoidf_(v);
                const ushort bv = f2b(v * sg);
                stg16(a1 + (size_t)(rowb + r) * HH + col, bv);
                pv[r] = bv;
                dsr[idx] = sg * (1.0f + v * (1.0f - sg));
            }
            stg64(a1t + (size_t)col * TOK + rowb, pack4(pv));
        }
}

__device__ __forceinline__ void op_s2(const ushort* a1, const ushort* W2e,
                                      const ushort* vt, ushort* db2, ushort* db2t,
                                      int m0, int n0, ushort* As, ushort* Bs) {
    f32x4 acc[2][2]; zacc(acc);
    gemm_core<true, true, 16>(a1, HH, W2e, HH, m0, n0, As, Bs, acc);
    const int lane = threadIdx.x & 63, w = threadIdx.x >> 6;
    const int wr = (w >> 1) * 32, wc = (w & 1) * 32;
    const int lr = lane & 15, lg = lane >> 4;
#pragma unroll
    for (int mi = 0; mi < 2; ++mi)
#pragma unroll
        for (int ni = 0; ni < 2; ++ni) {
            const int col = n0 + wc + ni * 16 + lr;
            const int rowb = m0 + wr + mi * 16 + lg * 4;
            ushort pv[4];
#pragma unroll
            for (int r = 0; r < 4; ++r) {
                const float v = acc[mi][ni][r];
                const float e = clip1f_(v - b2f(vt[(size_t)(rowb + r) * DD + col]));
                const ushort bv = f2b(e * ERRSCALE);
                stg16(db2 + (size_t)(rowb + r) * DD + col, bv);
                pv[r] = bv;
            }
            stg64(db2t + (size_t)col * TOK + rowb, pack4(pv));
        }
}

// s3: db1t = ((db2 @ W2e) * silu') written TRANSPOSED only (packed 8B).
__device__ __forceinline__ void op_s3(const ushort* db2, const ushort* W2eT,
                                      const float (&dsr)[16], ushort* db1t,
                                      int m0, int n0, ushort* As, ushort* Bs) {
    f32x4 acc[2][2]; zacc(acc);
    gemm_core<true, true, 8>(db2, DD, W2eT, DD, m0, n0, As, Bs, acc);
    const int lane = threadIdx.x & 63, w = threadIdx.x >> 6;
    const int wr = (w >> 1) * 32, wc = (w & 1) * 32;
    const int lr = lane & 15, lg = lane >> 4;
#pragma unroll
    for (int mi = 0; mi < 2; ++mi)
#pragma unroll
        for (int ni = 0; ni < 2; ++ni) {
            const int col = n0 + wc + ni * 16 + lr;
            const int rowb = m0 + wr + mi * 16 + lg * 4;
            ushort pv[4];
#pragma unroll
            for (int r = 0; r < 4; ++r) {
                const int idx = mi * 8 + ni * 4 + r;
                pv[r] = f2b(acc[mi][ni][r] * dsr[idx]);
            }
            stg64(db1t + (size_t)col * TOK + rowb, pack4(pv));
        }
}

// ktt transpose (P1, idle blocks 0-63): kt [TOK][DD] -> ktt [DD][TOK].
// ROUND-17 CHANGE: scatter on CACHED reads, coalesced 16B sc1 writes.
// Thread (d, mg): reads kt[mg*8+j][d] (j=0..7), writes ktt[d][mg*8..+8].
// Consecutive lanes cover consecutive mg -> contiguous 512B write runs.
__device__ __forceinline__ void op_ktt(const ushort* kt, ushort* ktt, int lbid) {
    const int g = lbid * 256 + threadIdx.x;       // 0..16383 = 512 d x 32 mg
    const int d = g >> 5;                         // 0..511
    const int mg = g & 31;                        // 0..31
    ushort u[8];
#pragma unroll
    for (int j = 0; j < 8; ++j) u[j] = kt[(size_t)(mg * 8 + j) * DD + d];
    f32x4 vv; __builtin_memcpy(&vv, u, 16);
    stg128v(ktt + (size_t)d * TOK + mg * 8, vv);
}

// Gradient GEMM + register-resident state update; publishes W_new
// (scattered stg16) and W_newT (packed 8B) for g2.
template<int LD, bool WT>
__device__ __forceinline__ void op_gupd(
    const ushort* __restrict__ At, const ushort* __restrict__ Bt,
    float (&sm)[16], float (&sd)[16], const float (&swm)[16],
    ushort* __restrict__ Wn, ushort* __restrict__ WnT,
    float dec, float lrg, float eta,
    int i0, int j0, ushort* As, ushort* Bs)
{
    f32x4 acc[2][2]; zacc(acc);
    gemm_core<true, true, 4>(At, TOK, Bt, TOK, i0, j0, As, Bs, acc);
    const int lane = threadIdx.x & 63, w = threadIdx.x >> 6;
    const int wr = (w >> 1) * 32, wc = (w & 1) * 32;
    const int lr = lane & 15, lg = lane >> 4;
#pragma unroll
    for (int mi = 0; mi < 2; ++mi)
#pragma unroll
        for (int ni = 0; ni < 2; ++ni) {
            const int col = j0 + wc + ni * 16 + lr;
            const int rowb = i0 + wr + mi * 16 + lg * 4;
            ushort pv[4];
#pragma unroll
            for (int r = 0; r < 4; ++r) {
                const int idx = mi * 8 + ni * 4 + r;
                const float g = clip1f_(acc[mi][ni][r]);
                const float mn = eta * sm[idx] - lrg * g;
                sm[idx] = mn;
                const float dn = (1.0f - dec) * sd[idx] + mn;
                sd[idx] = dn;
                const ushort wv = f2b(swm[idx] + dn);
                stg16(Wn + (size_t)(rowb + r) * LD + col, wv);
                pv[r] = wv;
            }
            if (WT) stg64(WnT + (size_t)col * DD + rowb, pack4(pv));
        }
}

__device__ __forceinline__ void op_s6(const ushort* qt, const ushort* W1e,
                                      ushort* h, int m0, int n0,
                                      ushort* As, ushort* Bs) {
    f32x4 acc[2][2]; zacc(acc);
    gemm_core<false, true, 8>(qt, DD, W1e, DD, m0, n0, As, Bs, acc);
    epilogue_i(m0, n0, acc, [&](int idx, int r, int c, float v) {
        const float sg = sigmoidf_(v);
        stg16(h + (size_t)r * HH + c, f2b(v * sg));
    });
}

__device__ __forceinline__ void op_s7(const ushort* h, const ushort* W2e,
                                      ushort* y, int m0, int n0,
                                      ushort* As, ushort* Bs) {
    f32x4 acc[2][2]; zacc(acc);
    gemm_core<true, true, 16>(h, HH, W2e, HH, m0, n0, As, Bs, acc);
    epilogue_i(m0, n0, acc, [&](int idx, int r, int c, float v) {
        stg16(y + (size_t)r * DD + c, f2b(v));
    });
}

// ---------------------------------------------------------------------------
// Persistent scan kernel (round-14 structure).
//   blocks   0- 63: ktt transpose (P1), s6/s7/s2 (P3/P4)
//   blocks  64-127: s1/s3 (same tiles -> silu' stays in registers)
//   blocks 128-255: g2 state tile AND g1 state tile (registers)
// 4 grid barriers per chunk:
//   P1 = ktt || s3(t) || g2upd(t); P2 = g1upd(t); P3 = s6(t) || s1(t+1);
//   P4 = s7(t) || s2(t+1).  Weights/activations parity double-buffered.
// ---------------------------------------------------------------------------
struct ScanArgs {
    const ushort *ktb, *vcb, *qtb;
    ushort *a1b0, *a1b1, *a1t0, *a1t1;
    ushort *db1t, *db2b0, *db2b1, *db2t0, *db2t1, *hbb, *kttb;
    ushort *W1eb0, *W1eb1, *W2eb0, *W2eb1, *W2eT0, *W2eT1;
    const float *Wm1, *Wm2, *gates;
    ushort *ycall;
    unsigned *flags, *gen;
};

__global__ __launch_bounds__(256, 1) void scan_k(ScanArgs p) {
    __shared__ ushort As[2 * 64 * SA];
    __shared__ ushort Bs[2 * 64 * SA];
    const int bid = blockIdx.x;
    unsigned bt = 0;

    const int lane = threadIdx.x & 63, w = threadIdx.x >> 6;
    const int wr = (w >> 1) * 32, wc = (w & 1) * 32;
    const int lr = lane & 15, lg = lane >> 4;

    float dsr[16];                                   // blocks 64-127
    float sm1[16], sd1[16], swm1[16];                // blocks 128-255: g1 tile [H,D]
    float sm2[16], sd2[16], swm2[16];                // blocks 128-255: g2 tile [D,H]
    int g1i0 = 0, g1j0 = 0, g2i0 = 0, g2j0 = 0;
    if (bid >= 128) {
        const int L = bid - 128;
        g2i0 = (L >> 4) * 64; g2j0 = (L & 15) * 64;
        g1i0 = (L >> 3) * 64; g1j0 = (L & 7) * 64;
#pragma unroll
        for (int mi = 0; mi < 2; ++mi)
#pragma unroll
            for (int ni = 0; ni < 2; ++ni)
#pragma unroll
                for (int r = 0; r < 4; ++r) {
                    const int idx = mi * 8 + ni * 4 + r;
                    const int ro = wr + mi * 16 + lg * 4 + r;
                    const int co = wc + ni * 16 + lr;
                    swm2[idx] = p.Wm2[(size_t)(g2i0 + ro) * HH + (g2j0 + co)];
                    swm1[idx] = p.Wm1[(size_t)(g1i0 + ro) * DD + (g1j0 + co)];
                    sm1[idx] = 0.0f; sd1[idx] = 0.0f;
                    sm2[idx] = 0.0f; sd2[idx] = 0.0f;
                }
    }

    // ---- prologue: chunk-0 forward ----
    if (bid >= 64 && bid < 128) {
        const int L = bid - 64;
        op_s1(p.ktb, p.W1eb0, p.a1b0, p.a1t0, dsr,
              (L >> 4) * 64, (L & 15) * 64, As, Bs);
    }
    gbar(p.flags, p.gen, ++bt);
    if (bid >= 32 && bid < 64) {
        const int L = bid - 32;
        op_s2(p.a1b0, p.W2eb0, p.vcb, p.db2b0, p.db2t0,
              (L >> 3) * 64, (L & 7) * 64, As, Bs);
    }
    gbar(p.flags, p.gen, ++bt);

    for (int t = 0; t < NCHK; ++t) {
        const int par = t & 1;
        const ushort* kt  = p.ktb + (size_t)t * TOK * DD;
        const ushort* qt  = p.qtb + (size_t)t * TOK * DD;
        ushort* a1n   = par ? p.a1b0 : p.a1b1;
        ushort* a1tn  = par ? p.a1t0 : p.a1t1;
        ushort* a1tc  = par ? p.a1t1 : p.a1t0;
        ushort* db2c  = par ? p.db2b1 : p.db2b0;
        ushort* db2n  = par ? p.db2b0 : p.db2b1;
        ushort* db2tc = par ? p.db2t1 : p.db2t0;
        ushort* db2tn = par ? p.db2t0 : p.db2t1;
        ushort* W1n   = par ? p.W1eb0 : p.W1eb1;
        const ushort* W2oT = par ? p.W2eT1 : p.W2eT0;
        ushort* W2n   = par ? p.W2eb0 : p.W2eb1;
        ushort* W2nT  = par ? p.W2eT0 : p.W2eT1;
        const float dec = p.gates[t];
        const float lrg = p.gates[NCHK + t];
        const float eta = p.gates[2 * NCHK + t];

        // P1: ktt (0-63) || s3 (64-127, dsr in regs) || g2upd (128-255)
        if (bid < 64) {
            op_ktt(kt, p.kttb, bid);
        } else if (bid < 128) {
            const int L = bid - 64;
            op_s3(db2c, W2oT, dsr, p.db1t, (L >> 4) * 64, (L & 15) * 64, As, Bs);
        } else {
            op_gupd<HH, true>(db2tc, a1tc, sm2, sd2, swm2, W2n, W2nT,
                              dec, lrg, eta, g2i0, g2j0, As, Bs);
        }
        gbar(p.flags, p.gen, ++bt);

        // P2: g1upd (128-255, reg state)
        if (bid >= 128) {
            op_gupd<DD, false>(p.db1t, p.kttb, sm1, sd1, swm1, W1n, nullptr,
                               dec, lrg, eta, g1i0, g1j0, As, Bs);
        }
        gbar(p.flags, p.gen, ++bt);

        // P3: s6(t) (0-63) || s1(t+1) (64-127)
        if (bid < 64) {
            op_s6(qt, W1n, p.hbb, (bid >> 4) * 64, (bid & 15) * 64, As, Bs);
        } else if (bid < 128 && t + 1 < NCHK) {
            const int L = bid - 64;
            op_s1(p.ktb + (size_t)(t + 1) * TOK * DD, W1n, a1n, a1tn, dsr,
                  (L >> 4) * 64, (L & 15) * 64, As, Bs);
        }
        gbar(p.flags, p.gen, ++bt);

        // P4: s7(t) (0-31) || s2(t+1) (32-63)
        if (bid < 32) {
            op_s7(p.hbb, W2n, p.ycall + (size_t)t * TOK * DD,
                  (bid >> 3) * 64, (bid & 7) * 64, As, Bs);
        } else if (bid < 64 && t + 1 < NCHK) {
            const int L = bid - 32;
            op_s2(a1n, W2n, p.vcb + (size_t)(t + 1) * TOK * DD, db2n, db2tn,
                  (L >> 3) * 64, (L & 7) * 64, As, Bs);
        }
        gbar(p.flags, p.gen, ++bt);
    }
}

// ---------------------------------------------------------------------------
// Pre/post kernels (separate launches; plain cached loads/stores)
// ---------------------------------------------------------------------------
__global__ __launch_bounds__(256) void conv_k(const float* __restrict__ s,
                                              ushort* __restrict__ d, int n4) {
    const int i = blockIdx.x * 256 + threadIdx.x;
    if (i < n4) {
        const float4 v = ((const float4*)s)[i];
        ushort4 o;
        o.x = f2b(v.x); o.y = f2b(v.y); o.z = f2b(v.z); o.w = f2b(v.w);
        ((ushort4*)d)[i] = o;
    }
}

// Transposed conversion: s [R][C] f32 -> d [C][R] bf16 (for initial W2eT)
__global__ __launch_bounds__(256) void convT_k(const float* __restrict__ s,
                                               ushort* __restrict__ d, int R, int C) {
    const int i = blockIdx.x * 256 + threadIdx.x;
    if (i < R * C) {
        const int r = i / C, c = i % C;
        d[(size_t)c * R + r] = f2b(s[i]);
    }
}

template<int OM>
__global__ __launch_bounds__(256) void proj_k(const ushort* __restrict__ xb,
                                              const ushort* __restrict__ Wb,
                                              float* __restrict__ df,
                                              ushort* __restrict__ db) {
    __shared__ ushort As[2 * 64 * SA], Bs[2 * 64 * SA];
    f32x4 acc[2][2]; zacc(acc);
    const int m0 = blockIdx.y * 64, n0 = blockIdx.x * 64;
    gemm_core<false, false, 8>(xb, DD, Wb, DD, m0, n0, As, Bs, acc);
    epilogue_i(m0, n0, acc, [&](int idx, int row, int col, float val) {
        const int b = row >> 12, s = row & (SS - 1);
        const int t = s >> 6, c = s & 63;
        const size_t orow = (size_t)((t << 8) | (b << 6) | c);
        if (OM == 0) df[orow * DD + col] = val;
        else         db[orow * DD + col] = f2b(val);
    });
}

__global__ __launch_bounds__(256) void l2n_k(const float* __restrict__ kp,
                                             const float* __restrict__ qp,
                                             ushort* __restrict__ kb,
                                             ushort* __restrict__ qb) {
    const float* src = blockIdx.y ? qp : kp;
    ushort* dst = blockIdx.y ? qb : kb;
    const int row = blockIdx.x * 4 + (threadIdx.x >> 6);
    const int lane = threadIdx.x & 63;
    const float4* p = (const float4*)(src + (size_t)row * DD);
    float4 v0 = p[lane], v1 = p[lane + 64];
    float ss = v0.x * v0.x + v0.y * v0.y + v0.z * v0.z + v0.w * v0.w
             + v1.x * v1.x + v1.y * v1.y + v1.z * v1.z + v1.w * v1.w;
#pragma unroll
    for (int m = 32; m >= 1; m >>= 1) ss += __shfl_xor(ss, m);
    const float sc = 1.0f / (sqrtf(ss) + 1e-8f);
    ushort4 o0, o1;
    o0.x = f2b(v0.x * sc); o0.y = f2b(v0.y * sc); o0.z = f2b(v0.z * sc); o0.w = f2b(v0.w * sc);
    o1.x = f2b(v1.x * sc); o1.y = f2b(v1.y * sc); o1.z = f2b(v1.z * sc); o1.w = f2b(v1.w * sc);
    *(ushort4*)(dst + (size_t)row * DD + lane * 4) = o0;
    *(ushort4*)(dst + (size_t)row * DD + 256 + lane * 4) = o1;
}

__global__ __launch_bounds__(256) void gates_tok_k(
    const float* __restrict__ x,
    const float* __restrict__ gdw, const float* __restrict__ gdb,
    const float* __restrict__ glw, const float* __restrict__ glb,
    const float* __restrict__ gmw, const float* __restrict__ gmb,
    float* __restrict__ gtok)
{
    const int wid = (blockIdx.x * 256 + threadIdx.x) >> 6;
    const int lane = threadIdx.x & 63;
    const int t = wid >> 8;
    const int rem = wid & 255;
    const int b = rem >> 6;
    const int c = rem & 63;
    const float* xr = x + ((size_t)b * SS + (size_t)t * CHK + c) * DD;
    float s0 = 0.0f, s1 = 0.0f, s2 = 0.0f;
#pragma unroll
    for (int jj = 0; jj < DD / 64; ++jj) {
        const int j = lane + jj * 64;
        const float xv = xr[j];
        s0 = fmaf(xv, gdw[j], s0);
        s1 = fmaf(xv, glw[j], s1);
        s2 = fmaf(xv, gmw[j], s2);
    }
#pragma unroll
    for (int m = 32; m >= 1; m >>= 1) {
        s0 += __shfl_xor(s0, m);
        s1 += __shfl_xor(s1, m);
        s2 += __shfl_xor(s2, m);
    }
    if (lane == 0) {
        gtok[0 * (NCHK * TOK) + wid] = sigmoidf_(s0 + gdb[0]);
        gtok[1 * (NCHK * TOK) + wid] = sigmoidf_(s1 + glb[0]);
        gtok[2 * (NCHK * TOK) + wid] = sigmoidf_(s2 + gmb[0]);
    }
}

__global__ __launch_bounds__(256) void gates_red_k(
    const float* __restrict__ gtok, float* __restrict__ gates)
{
    __shared__ float sm[256];
    const int t = blockIdx.x;
    for (int g = 0; g < 3; ++g) {
        sm[threadIdx.x] = gtok[g * (NCHK * TOK) + t * TOK + threadIdx.x];
        __syncthreads();
        for (int s = 128; s >= 1; s >>= 1) {
            if (threadIdx.x < s) sm[threadIdx.x] += sm[threadIdx.x + s];
            __syncthreads();
        }
        if (threadIdx.x == 0) gates[g * NCHK + t] = sm[0] * (1.0f / 256.0f);
        __syncthreads();
    }
}

__global__ __launch_bounds__(256) void out_k(const ushort* __restrict__ ycall,
                                             const ushort* __restrict__ Woutb,
                                             float* __restrict__ out) {
    __shared__ ushort As[2 * 64 * SA], Bs[2 * 64 * SA];
    f32x4 acc[2][2]; zacc(acc);
    const int m0 = blockIdx.y * 64, n0 = blockIdx.x * 64;
    gemm_core<false, false, 8>(ycall, DD, Woutb, DD, m0, n0, As, Bs, acc);
    epilogue_i(m0, n0, acc, [&](int idx, int row, int col, float val) {
        const int t = row >> 8, b = (row >> 6) & 3, c = row & 63;
        out[((size_t)b * SS + (size_t)t * CHK + c) * DD + col] = val;
    });
}

// ---------------------------------------------------------------------------
extern "C" void kernel_launch(void* const* d_in, const int* in_sizes, int n_in,
                              void* d_out, int out_size, void* d_ws, size_t ws_size,
                              hipStream_t stream)
{
    const float* x    = (const float*)d_in[0];
    const float* Wk   = (const float*)d_in[1];
    const float* Wv   = (const float*)d_in[2];
    const float* Wq   = (const float*)d_in[3];
    const float* Wout = (const float*)d_in[4];
    const float* Wm1  = (const float*)d_in[5];
    const float* Wm2  = (const float*)d_in[6];
    const float* gdw  = (const float*)d_in[7];
    const float* gdb  = (const float*)d_in[8];
    const float* glw  = (const float*)d_in[9];
    const float* glb  = (const float*)d_in[10];
    const float* gmw  = (const float*)d_in[11];
    const float* gmb  = (const float*)d_in[12];
    float* out = (float*)d_out;

    char* w = (char*)d_ws;
    size_t off = 0;
    auto alloc = [&](size_t bytes) {
        off = (off + 255) & ~(size_t)255;
        char* p = w + off;
        off += bytes;
        return p;
    };

    const size_t M = (size_t)BB * SS;                 // 16384
    float*  kpre = (float*)alloc(M * DD * 4);         // f32 chunk-major; ycall aliases
    char*   qreg = alloc(M * DD * 4);                 // qpre f32; scan temps alias after l2n
    float*  qpre = (float*)qreg;
    ushort* xb   = (ushort*)alloc(M * DD * 2);        // ktb aliases after projections
    ushort* qtb  = (ushort*)alloc(M * DD * 2);
    ushort* vcb  = (ushort*)alloc(M * DD * 2);
    ushort* Wkb  = (ushort*)alloc((size_t)DD * DD * 2);
    ushort* Wvb  = (ushort*)alloc((size_t)DD * DD * 2);
    ushort* Wqb  = (ushort*)alloc((size_t)DD * DD * 2);
    ushort* Woutb= (ushort*)alloc((size_t)DD * DD * 2);
    float*  gtok = (float*)alloc((size_t)3 * NCHK * TOK * 4);
    float*  gates= (float*)alloc((size_t)3 * NCHK * 4);
    unsigned* bar = (unsigned*)alloc((size_t)(GRID_BLKS * FLAG_STRIDE + 64) * 4);

    ushort* ktb   = xb;             // alias: xb dead after projection GEMMs
    ushort* ycall = (ushort*)kpre;  // alias: kpre dead after l2norm

    // scan temporaries carved from qpre region (dead after l2n):
    size_t qo = 0;
    auto qalloc = [&](size_t bytes) { char* p = qreg + qo; qo += bytes; return p; };
    ushort* a1b0  = (ushort*)qalloc((size_t)TOK * HH * 2);
    ushort* a1b1  = (ushort*)qalloc((size_t)TOK * HH * 2);
    ushort* a1t0  = (ushort*)qalloc((size_t)TOK * HH * 2);
    ushort* a1t1  = (ushort*)qalloc((size_t)TOK * HH * 2);
    ushort* db1t  = (ushort*)qalloc((size_t)TOK * HH * 2);
    ushort* db2b0 = (ushort*)qalloc((size_t)TOK * DD * 2);
    ushort* db2b1 = (ushort*)qalloc((size_t)TOK * DD * 2);
    ushort* db2t0 = (ushort*)qalloc((size_t)TOK * DD * 2);
    ushort* db2t1 = (ushort*)qalloc((size_t)TOK * DD * 2);
    ushort* hbb   = (ushort*)qalloc((size_t)TOK * HH * 2);
    ushort* kttb  = (ushort*)qalloc((size_t)TOK * DD * 2);
    ushort* W1eb0 = (ushort*)qalloc((size_t)HH * DD * 2);
    ushort* W1eb1 = (ushort*)qalloc((size_t)HH * DD * 2);
    ushort* W2eb0 = (ushort*)qalloc((size_t)HH * DD * 2);
    ushort* W2eb1 = (ushort*)qalloc((size_t)HH * DD * 2);
    ushort* W2eT0 = (ushort*)qalloc((size_t)HH * DD * 2);
    ushort* W2eT1 = (ushort*)qalloc((size_t)HH * DD * 2);

    // zero the barrier flags/gen
    hipMemsetAsync(bar, 0, (size_t)(GRID_BLKS * FLAG_STRIDE + 64) * 4, stream);

    const dim3 blk(256);

    // bf16 conversions of x and projection weights
    conv_k<<<dim3((M * DD / 4 + 255) / 256), blk, 0, stream>>>(x, xb, (int)(M * DD / 4));
    conv_k<<<dim3((DD * DD / 4 + 255) / 256), blk, 0, stream>>>(Wk, Wkb, DD * DD / 4);
    conv_k<<<dim3((DD * DD / 4 + 255) / 256), blk, 0, stream>>>(Wv, Wvb, DD * DD / 4);
    conv_k<<<dim3((DD * DD / 4 + 255) / 256), blk, 0, stream>>>(Wq, Wqb, DD * DD / 4);
    conv_k<<<dim3((DD * DD / 4 + 255) / 256), blk, 0, stream>>>(Wout, Woutb, DD * DD / 4);

    // projections (chunk-major epilogue)
    proj_k<0><<<dim3(DD / 64, M / 64), blk, 0, stream>>>(xb, Wkb, kpre, nullptr);
    proj_k<1><<<dim3(DD / 64, M / 64), blk, 0, stream>>>(xb, Wvb, nullptr, vcb);
    proj_k<0><<<dim3(DD / 64, M / 64), blk, 0, stream>>>(xb, Wqb, qpre, nullptr);

    // l2norm + bf16 (ktb aliases xb; qpre consumed here)
    l2n_k<<<dim3(M / 4, 2), blk, 0, stream>>>(kpre, qpre, ktb, qtb);

    // initial effective weights (into qpre region — now dead)
    conv_k<<<dim3((HH * DD / 4 + 255) / 256), blk, 0, stream>>>(Wm1, W1eb0, HH * DD / 4);
    conv_k<<<dim3((HH * DD / 4 + 255) / 256), blk, 0, stream>>>(Wm2, W2eb0, HH * DD / 4);
    convT_k<<<dim3((DD * HH + 255) / 256), blk, 0, stream>>>(Wm2, W2eT0, DD, HH);

    // gates
    gates_tok_k<<<dim3(M / 4), blk, 0, stream>>>(x, gdw, gdb, glw, glb, gmw, gmb, gtok);
    gates_red_k<<<dim3(NCHK), blk, 0, stream>>>(gtok, gates);

    // persistent scan (all 64 chunks)
    ScanArgs sa;
    sa.ktb = ktb; sa.vcb = vcb; sa.qtb = qtb;
    sa.a1b0 = a1b0; sa.a1b1 = a1b1; sa.a1t0 = a1t0; sa.a1t1 = a1t1;
    sa.db1t = db1t; sa.db2b0 = db2b0; sa.db2b1 = db2b1;
    sa.db2t0 = db2t0; sa.db2t1 = db2t1; sa.hbb = hbb; sa.kttb = kttb;
    sa.W1eb0 = W1eb0; sa.W1eb1 = W1eb1; sa.W2eb0 = W2eb0; sa.W2eb1 = W2eb1;
    sa.W2eT0 = W2eT0; sa.W2eT1 = W2eT1;
    sa.Wm1 = Wm1; sa.Wm2 = Wm2; sa.gates = gates;
    sa.ycall = ycall;
    sa.flags = bar; sa.gen = bar + GRID_BLKS * FLAG_STRIDE;
    scan_k<<<dim3(GRID_BLKS), blk, 0, stream>>>(sa);

    // final projection + scatter to [B,S,D]
    out_k<<<dim3(DD / 64, M / 64), blk, 0, stream>>>(ycall, Woutb, out);
}